// Round 8
// baseline (817.804 us; speedup 1.0000x reference)
//
#include <hip/hip_runtime.h>
#include <stdint.h>

typedef float f32x4 __attribute__((ext_vector_type(4)));
typedef __bf16 bf16x8 __attribute__((ext_vector_type(8)));
typedef unsigned short ushort4v __attribute__((ext_vector_type(4)));

#define DIM 4608
#define BK 32
#define NT 16
#define WS_L_BYTES (16 * 4 * 512 * 16)  // 512 KiB per l: 16 k-steps x [grp4][col512][8 bf16]

// ---------------- prepack: W (fp32) -> ws (bf16, c folded, B-fragment order) ----------------
__global__ __launch_bounds__(256) void prepack(const float* __restrict__ W0,
                                               const float* __restrict__ W1,
                                               const float* __restrict__ W2,
                                               char* __restrict__ ws) {
  int gid = blockIdx.x * 256 + threadIdx.x;  // 3*16*4*512 = 98304 threads
  int col = gid & 511;
  int rest = gid >> 9;
  int grp = rest & 3;
  rest >>= 2;
  int t = rest & 15;
  int l = rest >> 4;
  const float* W = (l == 0) ? W0 : ((l == 1) ? W1 : W2);
  const float c = 0.044194173824159216f;  // 1/sqrt(512) path normalization
  union {
    bf16x8 v;
    uint4 u;
  } pk;
#pragma unroll
  for (int jj = 0; jj < 8; ++jj) {
    float v = W[(t * 32 + grp * 8 + jj) * 512 + col] * c;
    pk.v[jj] = (__bf16)v;
  }
  *(uint4*)(ws + (size_t)l * WS_L_BYTES + ((size_t)((t * 4 + grp) * 512 + col) << 4)) = pk.u;
}

// ---------------- wave-private per-l GEMM body: NO barriers anywhere ----------------
// Block = 8 waves, one z-chunk (BZ z) x 256 cols (j half). Each WAVE owns: a private LDS
// frag buffer (single-buffered; in-order LDS pipe makes write(t+1)-after-read(t) safe
// within a wave), a 32-col output strip, and its own pipeline. All waits are per-wave
// compiler-counted vmcnt/lgkmcnt. Waves share the z-chunk's A-tile via L1/L2 (same CU).
template <int D, int BZ, int OFF>
__device__ __forceinline__ void gemm_body(int zc, int j, const float* __restrict__ x1,
                                          const float* __restrict__ x2,
                                          const char* __restrict__ wsl,
                                          float* __restrict__ out,
                                          char* __restrict__ smem) {
  constexpr int BM = BZ * D;       // rows (z,i) per wave tile
  constexpr int R = BM / 16;       // 16-row MFMA tiles
  constexpr int WBYTES = BM * 64;  // per-wave bf16 frag buffer (BM * BK * 2)
  constexpr int PF = BZ * 8 * D / 64;  // f32x4 quads per lane per tile

  const int tid = threadIdx.x;
  const int lane = tid & 63;
  const int wave = tid >> 6;
  const int llo = lane & 15;
  const int lhi = lane >> 4;

  char* wbuf = smem + wave * WBYTES;  // wave-private

  const int z0 = zc * BZ;
  const int cb = j * 256;
  const float* xbase = x1 + (size_t)z0 * DIM + OFF;

  f32x4 acc[R][2];
#pragma unroll
  for (int rt = 0; rt < R; ++rt)
#pragma unroll
    for (int ct = 0; ct < 2; ++ct) acc[rt][ct] = (f32x4){0.f, 0.f, 0.f, 0.f};

  f32x4 pa[PF];
  bf16x8 b[2];

  auto load_a = [&](int t) {
    const float* xs = xbase + t * (BK * D);
#pragma unroll
    for (int s = 0; s < PF; ++s) {
      int idx = lane + s * 64;
      int zl = idx / (8 * D);
      int q = idx - zl * (8 * D);
      pa[s] = *(const f32x4*)(xs + (size_t)zl * DIM + q * 4);
    }
  };

  auto load_b = [&](int t) {
    const char* wt = wsl + (size_t)t * 32768;
#pragma unroll
    for (int ct = 0; ct < 2; ++ct)
      b[ct] = *(const bf16x8*)(wt + ((lhi * 512 + cb + wave * 32 + ct * 16 + llo) << 4));
  };

  auto stage = [&]() {
#pragma unroll
    for (int s = 0; s < PF; ++s) {
      int idx = lane + s * 64;
      int zl = idx / (8 * D);
      int q = idx - zl * (8 * D);
      if (D == 1) {
        int u0 = q * 4;  // 4 consecutive u, same row -> one 8B write
        union {
          ushort4v us;
          __bf16 b4[4];
        } pk;
#pragma unroll
        for (int e = 0; e < 4; ++e) pk.b4[e] = (__bf16)pa[s][e];
        *(ushort4v*)(wbuf + ((u0 >> 3) * BM + zl) * 16 + (u0 & 7) * 2) = pk.us;
      } else {
#pragma unroll
        for (int e = 0; e < 4; ++e) {
          int f = q * 4 + e;
          int u = f / D;
          int i = f - u * D;
          int r = zl * D + i;
          *(__bf16*)(wbuf + ((u >> 3) * BM + r) * 16 + (u & 7) * 2) = (__bf16)pa[s][e];
        }
      }
    }
  };

  auto compute = [&]() {
#pragma unroll
    for (int rt = 0; rt < R; ++rt) {
      bf16x8 af = *(const bf16x8*)(wbuf + ((lhi * BM + rt * 16 + llo) << 4));
#pragma unroll
      for (int ct = 0; ct < 2; ++ct)
        acc[rt][ct] = __builtin_amdgcn_mfma_f32_16x16x32_bf16(af, b[ct], acc[rt][ct], 0, 0, 0);
    }
  };

  // ---- per-wave pipeline: 1-deep A prefetch, b loaded in-phase ----
  load_a(0);
#pragma unroll 1
  for (int t = 0; t < NT - 1; ++t) {
    stage();        // waits pa(t) (counted vmcnt), fills wave-private frag buffer
    load_a(t + 1);  // in flight across compute(t) + next stage-wait
    load_b(t);      // L2-resident ws; ~200cyc hidden under lgkm-wait + ds_reads
    compute();      // lgkmcnt orders own ds_writes -> ds_reads; MFMA
  }
  stage();
  load_b(NT - 1);
  compute();

  // ---- epilogue: C/D layout col=lane&15, row=(lane>>4)*4+reg; fold x2[z] here ----
  float* obase = out + (size_t)z0 * DIM + OFF;
#pragma unroll
  for (int rt = 0; rt < R; ++rt) {
#pragma unroll
    for (int reg = 0; reg < 4; ++reg) {
      int row = rt * 16 + lhi * 4 + reg;
      int z = row / D;
      int i = row - z * D;
      float s = x2[z0 + z];
#pragma unroll
      for (int ct = 0; ct < 2; ++ct) {
        int col = cb + wave * 32 + ct * 16 + llo;
        obase[(size_t)z * DIM + col * D + i] = acc[rt][ct][reg] * s;
      }
    }
  }
}

// Fused: [0,2048) -> l2, [2048,4096) -> l1, [4096,6144) -> l0.
// zc = b>>1, j = b&1: the two col-halves of a z-chunk are adjacent bids (R4-proven
// FETCH-neutral). Blocks cover all 256 cols x BZ z -> write regions are wide & aligned.
__global__ __launch_bounds__(512, 4) void gemm_fused(const float* __restrict__ x1,
                                                     const float* __restrict__ x2,
                                                     const char* __restrict__ ws,
                                                     float* __restrict__ out) {
  // 8 waves x max per-wave frag buffer (l2: 5120 B) = 40 KiB -> 2 blocks/CU fits LDS.
  __shared__ __align__(16) char smem[8 * 5120];
  int bid = blockIdx.x;
  if (bid < 2048) {
    gemm_body<5, 16, 2048>(bid >> 1, bid & 1, x1, x2, ws + 2 * (size_t)WS_L_BYTES, out, smem);
  } else if (bid < 4096) {
    int b = bid - 2048;
    gemm_body<3, 16, 512>(b >> 1, b & 1, x1, x2, ws + (size_t)WS_L_BYTES, out, smem);
  } else {
    int b = bid - 4096;
    gemm_body<1, 16, 0>(b >> 1, b & 1, x1, x2, ws, out, smem);
  }
}

extern "C" void kernel_launch(void* const* d_in, const int* in_sizes, int n_in,
                              void* d_out, int out_size, void* d_ws, size_t ws_size,
                              hipStream_t stream) {
  const float* x1 = (const float*)d_in[0];
  const float* x2 = (const float*)d_in[1];
  const float* W0 = (const float*)d_in[2];
  const float* W1 = (const float*)d_in[3];
  const float* W2 = (const float*)d_in[4];
  float* out = (float*)d_out;
  char* ws = (char*)d_ws;

  prepack<<<384, 256, 0, stream>>>(W0, W1, W2, ws);
  gemm_fused<<<6144, 512, 0, stream>>>(x1, x2, ws, out);
}

// Round 9
// 407.587 us; speedup vs baseline: 2.0065x; 2.0065x over previous
//
#include <hip/hip_runtime.h>
#include <stdint.h>

typedef float f32x4 __attribute__((ext_vector_type(4)));
typedef __bf16 bf16x8 __attribute__((ext_vector_type(8)));
typedef unsigned short ushort4v __attribute__((ext_vector_type(4)));

#define DIM 4608
#define NZ 16384
#define WS_L_BYTES (16 * 4 * 512 * 16)  // 512 KiB per l: W bf16, c folded, B-frag order
#define XT_OFF ((size_t)2 << 20)

#define MFMA16 __builtin_amdgcn_mfma_f32_16x16x32_bf16

// ---------------- prepack: W (fp32) -> ws (bf16, c folded, B-fragment order) ----------------
__global__ __launch_bounds__(256) void prepack(const float* __restrict__ W0,
                                               const float* __restrict__ W1,
                                               const float* __restrict__ W2,
                                               char* __restrict__ ws) {
  int gid = blockIdx.x * 256 + threadIdx.x;  // 3*16*4*512 = 98304 threads
  int col = gid & 511;
  int rest = gid >> 9;
  int grp = rest & 3;
  rest >>= 2;
  int t = rest & 15;
  int l = rest >> 4;
  const float* W = (l == 0) ? W0 : ((l == 1) ? W1 : W2);
  const float c = 0.044194173824159216f;  // 1/sqrt(512) path normalization
  union {
    bf16x8 v;
    uint4 u;
  } pk;
#pragma unroll
  for (int jj = 0; jj < 8; ++jj) {
    float v = W[(t * 32 + grp * 8 + jj) * 512 + col] * c;
    pk.v[jj] = (__bf16)v;
  }
  *(uint4*)(ws + (size_t)l * WS_L_BYTES + ((size_t)((t * 4 + grp) * 512 + col) << 4)) = pk.u;
}

// ---------------- xpack: x1 (fp32, D-interleaved) -> xt (bf16 A-fragments, x2 folded) -------
// Unit (tk, r): 16B = bf16 x2[z]*x1[z, OFF + (tk*8+j)*D + i], j=0..7, where r = zloc*D+i.
// xt addr = (tk*NRC + r)*16, NRC = CZ*D. Writes: lanes -> consecutive r -> 1KB/wave coalesced.
// Reads: 8 scalars stride 4D per thread; a thread's 8 reads span one dense 32D-float run.
template <int D, int OFF>
__global__ __launch_bounds__(256) void xpack(const float* __restrict__ x1,
                                             const float* __restrict__ x2,
                                             char* __restrict__ xt, int z0, int CZ) {
  const int NRC = CZ * D;
  int gid = blockIdx.x * 256 + threadIdx.x;  // 64 * NRC threads
  int tk = gid / NRC;
  int rl = gid - tk * NRC;
  int zl = rl / D;
  int i = rl - zl * D;
  const float* src = x1 + (size_t)(z0 + zl) * DIM + OFF + (tk * 8) * D + i;
  float s = x2[z0 + zl];
  union {
    bf16x8 v;
    uint4 u;
  } pk;
#pragma unroll
  for (int j = 0; j < 8; ++j) pk.v[j] = (__bf16)(src[j * D] * s);
  *(uint4*)(xt + ((size_t)tk * NRC + rl) * 16) = pk.u;
}

// ---------------- gemmx: LDS-free streaming MFMA GEMM on prepacked xt/ws ----------------
// Block: 512 thr / 8 waves, BM=64 rows (4 row-tiles), wave = 64 cols (4 col-tiles).
// All loads are direct, coalesced, compiler-counted; NO data barriers. A pacing s_barrier
// every 4 k-tiles bounds intra-block drift so the 8 waves share each A-slab via L1 (R8 lesson).
template <int D, int OFF>
__global__ __launch_bounds__(512, 4) void gemmx(const char* __restrict__ xt,
                                                const char* __restrict__ wsl,
                                                float* __restrict__ out, int z0, int CZ) {
  const int NRC = CZ * D;
  const int tid = threadIdx.x;
  const int lane = tid & 63;
  const int wave = tid >> 6;
  const int llo = lane & 15;
  const int lhi = lane >> 4;
  const int rbase = blockIdx.x * 64;
  const int cb = wave * 64;

  f32x4 acc[4][4];
#pragma unroll
  for (int rt = 0; rt < 4; ++rt)
#pragma unroll
    for (int ct = 0; ct < 4; ++ct) acc[rt][ct] = (f32x4){0.f, 0.f, 0.f, 0.f};

  const char* abase = xt + ((size_t)lhi * NRC + rbase + llo) * 16;
  const char* bbase = wsl + ((size_t)(lhi * 512 + cb + llo)) * 16;

#pragma unroll
  for (int kt = 0; kt < 16; ++kt) {
    if ((kt & 3) == 0) __builtin_amdgcn_s_barrier();  // pacing only: bounds wave drift
    bf16x8 a[4], b[4];
#pragma unroll
    for (int rt = 0; rt < 4; ++rt)
      a[rt] = *(const bf16x8*)(abase + ((size_t)kt * 4 * NRC + rt * 16) * 16);
#pragma unroll
    for (int ct = 0; ct < 4; ++ct)
      b[ct] = *(const bf16x8*)(bbase + ((size_t)kt * 4 * 512 + ct * 16) * 16);
#pragma unroll
    for (int rt = 0; rt < 4; ++rt)
#pragma unroll
      for (int ct = 0; ct < 4; ++ct)
        acc[rt][ct] = MFMA16(a[rt], b[ct], acc[rt][ct], 0, 0, 0);
  }

  // epilogue: C/D layout col=lane&15, row=(lane>>4)*4+reg (x2 already folded into xt)
#pragma unroll
  for (int rt = 0; rt < 4; ++rt) {
#pragma unroll
    for (int reg = 0; reg < 4; ++reg) {
      int row = rbase + rt * 16 + lhi * 4 + reg;
      int z = row / D;
      int i = row - z * D;
      float* orow = out + (size_t)(z0 + z) * DIM + OFF + i;
#pragma unroll
      for (int ct = 0; ct < 4; ++ct) {
        int col = cb + ct * 16 + llo;
        orow[col * D] = acc[rt][ct][reg];
      }
    }
  }
}

// ---------------- fallback (ws too small): round-3 kernel, 218 us proven ----------------
#define BAR()                                        \
  do {                                               \
    __builtin_amdgcn_sched_barrier(0);               \
    asm volatile("s_waitcnt lgkmcnt(0)");            \
    __builtin_amdgcn_s_barrier();                    \
    __builtin_amdgcn_sched_barrier(0);               \
  } while (0)

template <int D, int BZ, int OFF>
__global__ __launch_bounds__(512) void gemm_l(const float* __restrict__ x1,
                                              const float* __restrict__ x2,
                                              const char* __restrict__ wsl,
                                              float* __restrict__ out) {
  constexpr int BM = BZ * D;
  constexpr int R = BM / 16;
  constexpr int ABYTES = BM * 64;
  constexpr int CNT = BZ * 8 * D;
  constexpr int PF = (CNT + 511) / 512;
  __shared__ __align__(16) char smem[2 * ABYTES];
  const int tid = threadIdx.x;
  const int z0 = blockIdx.x * BZ;
  const float* xbase = x1 + (size_t)z0 * DIM + OFF;
  const int lane = tid & 63;
  const int wave = tid >> 6;
  const int llo = lane & 15;
  const int lhi = lane >> 4;
  f32x4 acc[R][4];
#pragma unroll
  for (int rt = 0; rt < R; ++rt)
#pragma unroll
    for (int ct = 0; ct < 4; ++ct) acc[rt][ct] = (f32x4){0.f, 0.f, 0.f, 0.f};
  auto load_a = [&](f32x4(&pa)[PF], int t) {
    const float* xs = xbase + t * (32 * D);
#pragma unroll
    for (int s = 0; s < PF; ++s) {
      int idx = tid + s * 512;
      if (idx < CNT) {
        int zl = idx / (8 * D);
        int q = idx - zl * (8 * D);
        pa[s] = *(const f32x4*)(xs + (size_t)zl * DIM + q * 4);
      }
    }
  };
  auto load_b = [&](bf16x8(&b)[4], int t) {
    const char* wt = wsl + (size_t)t * 32768;
#pragma unroll
    for (int ct = 0; ct < 4; ++ct)
      b[ct] = *(const bf16x8*)(wt + ((lhi * 512 + wave * 64 + ct * 16 + llo) << 4));
  };
  auto stage_write = [&](char* buf, f32x4(&pa)[PF]) {
#pragma unroll
    for (int s = 0; s < PF; ++s) {
      int idx = tid + s * 512;
      if (idx < CNT) {
        int zl = idx / (8 * D);
        int q = idx - zl * (8 * D);
        if (D == 1) {
          int u0 = q * 4;
          union {
            ushort4v us;
            __bf16 b4[4];
          } pk;
#pragma unroll
          for (int e = 0; e < 4; ++e) pk.b4[e] = (__bf16)pa[s][e];
          *(ushort4v*)(buf + ((u0 >> 3) * BM + zl) * 16 + (u0 & 7) * 2) = pk.us;
        } else {
#pragma unroll
          for (int e = 0; e < 4; ++e) {
            int cl = q * 4 + e;
            int u = cl / D;
            int i = cl - u * D;
            int r = zl * D + i;
            *(__bf16*)(buf + ((u >> 3) * BM + r) * 16 + (u & 7) * 2) = (__bf16)pa[s][e];
          }
        }
      }
    }
  };
  auto compute = [&](const char* buf, bf16x8(&b)[4]) {
#pragma unroll
    for (int rt = 0; rt < R; ++rt) {
      bf16x8 af = *(const bf16x8*)(buf + ((lhi * BM + rt * 16 + llo) << 4));
#pragma unroll
      for (int ct = 0; ct < 4; ++ct)
        acc[rt][ct] = MFMA16(af, b[ct], acc[rt][ct], 0, 0, 0);
    }
  };
  f32x4 paE[PF], paO[PF];
  bf16x8 bE[4], bO[4];
  load_a(paE, 0);
  load_b(bE, 0);
  load_a(paO, 1);
  load_b(bO, 1);
  stage_write(smem, paE);
  load_a(paE, 2);
  BAR();
#pragma unroll
  for (int tt = 0; tt < 8; ++tt) {
    const int t = 2 * tt;
    compute(smem, bE);
    if (t + 2 < 16) load_b(bE, t + 2);
    stage_write(smem + ABYTES, paO);
    if (t + 3 < 16) load_a(paO, t + 3);
    BAR();
    compute(smem + ABYTES, bO);
    if (t + 3 < 16) load_b(bO, t + 3);
    if (t + 2 < 16) {
      stage_write(smem, paE);
      if (t + 4 < 16) load_a(paE, t + 4);
      BAR();
    }
  }
  float* obase = out + (size_t)z0 * DIM + OFF;
#pragma unroll
  for (int rt = 0; rt < R; ++rt) {
#pragma unroll
    for (int reg = 0; reg < 4; ++reg) {
      int row = rt * 16 + lhi * 4 + reg;
      int z = row / D;
      int i = row - z * D;
      float s = x2[z0 + z];
#pragma unroll
      for (int ct = 0; ct < 4; ++ct) {
        int col = wave * 64 + ct * 16 + llo;
        obase[(size_t)z * DIM + col * D + i] = acc[rt][ct][reg] * s;
      }
    }
  }
}

extern "C" void kernel_launch(void* const* d_in, const int* in_sizes, int n_in,
                              void* d_out, int out_size, void* d_ws, size_t ws_size,
                              hipStream_t stream) {
  const float* x1 = (const float*)d_in[0];
  const float* x2 = (const float*)d_in[1];
  const float* W0 = (const float*)d_in[2];
  const float* W1 = (const float*)d_in[3];
  const float* W2 = (const float*)d_in[4];
  float* out = (float*)d_out;
  char* ws = (char*)d_ws;

  prepack<<<384, 256, 0, stream>>>(W0, W1, W2, ws);

  // pick the largest z-chunk whose xt fits in ws: xt bytes = CZ * (1+3+5) * 64 * 16 = CZ*9216
  int CZ = 0;
  for (int cz = NZ; cz >= 2048; cz >>= 1)
    if (XT_OFF + (size_t)cz * 9216 <= ws_size) {
      CZ = cz;
      break;
    }

  if (CZ) {
    char* xt0 = ws + XT_OFF;
    char* xt1 = xt0 + (size_t)CZ * 1024;
    char* xt2 = xt1 + (size_t)CZ * 3072;
    for (int z0 = 0; z0 < NZ; z0 += CZ) {
      xpack<1, 0><<<CZ * 1 / 4, 256, 0, stream>>>(x1, x2, xt0, z0, CZ);
      xpack<3, 512><<<CZ * 3 / 4, 256, 0, stream>>>(x1, x2, xt1, z0, CZ);
      xpack<5, 2048><<<CZ * 5 / 4, 256, 0, stream>>>(x1, x2, xt2, z0, CZ);
      gemmx<1, 0><<<CZ * 1 / 64, 512, 0, stream>>>(xt0, ws, out, z0, CZ);
      gemmx<3, 512><<<CZ * 3 / 64, 512, 0, stream>>>(xt1, ws + WS_L_BYTES, out, z0, CZ);
      gemmx<5, 2048><<<CZ * 5 / 64, 512, 0, stream>>>(xt2, ws + 2 * (size_t)WS_L_BYTES, out, z0, CZ);
    }
  } else {
    gemm_l<1, 64, 0><<<256, 512, 0, stream>>>(x1, x2, ws, out);
    gemm_l<3, 16, 512><<<1024, 512, 0, stream>>>(x1, x2, ws + WS_L_BYTES, out);
    gemm_l<5, 16, 2048><<<1024, 512, 0, stream>>>(x1, x2, ws + 2 * (size_t)WS_L_BYTES, out);
  }
}

// Round 11
// 243.088 us; speedup vs baseline: 3.3642x; 1.6767x over previous
//
#include <hip/hip_runtime.h>
#include <stdint.h>

typedef float f32x4 __attribute__((ext_vector_type(4)));
typedef __bf16 bf16x8 __attribute__((ext_vector_type(8)));

#define DIM 4608
#define BK 32
#define NT 16
#define WS_L_BYTES (16 * 4 * 512 * 16)  // 512 KiB per l: W bf16, c folded, B-frag order

#define MFMA16 __builtin_amdgcn_mfma_f32_16x16x32_bf16
#define SB() __builtin_amdgcn_sched_barrier(0)

// ENTRY: counted-vmcnt barrier. Per wave outstanding = [dma(t) x KD, b(t) x 2] (uniform by
// construction). vmcnt(2) retires all dma(t), leaves the 2 newest (B regs) in flight.
// No vmcnt(0) drain anywhere in the loop — next-tile DMA always spans the barrier.
#define ENTRY()                                      \
  do {                                               \
    SB();                                            \
    asm volatile("s_waitcnt vmcnt(2)" ::: "memory"); \
    __builtin_amdgcn_s_barrier();                    \
    SB();                                            \
  } while (0)

// Frag-visibility barrier: own LDS ops done; VMEM untouched.
#define LGKMBAR()                                      \
  do {                                                 \
    SB();                                              \
    asm volatile("s_waitcnt lgkmcnt(0)" ::: "memory"); \
    __builtin_amdgcn_s_barrier();                      \
    SB();                                              \
  } while (0)

// ---------------- prepack: W (fp32) -> ws (bf16, c folded, B-fragment order) ----------------
__global__ __launch_bounds__(256) void prepack(const float* __restrict__ W0,
                                               const float* __restrict__ W1,
                                               const float* __restrict__ W2,
                                               char* __restrict__ ws) {
  int gid = blockIdx.x * 256 + threadIdx.x;  // 3*16*4*512 = 98304 threads
  int col = gid & 511;
  int rest = gid >> 9;
  int grp = rest & 3;
  rest >>= 2;
  int t = rest & 15;
  int l = rest >> 4;
  const float* W = (l == 0) ? W0 : ((l == 1) ? W1 : W2);
  const float c = 0.044194173824159216f;  // 1/sqrt(512) path normalization
  union {
    bf16x8 v;
    uint4 u;
  } pk;
#pragma unroll
  for (int jj = 0; jj < 8; ++jj) {
    float v = W[(t * 32 + grp * 8 + jj) * 512 + col] * c;
    pk.v[jj] = (__bf16)v;
  }
  *(uint4*)(ws + (size_t)l * WS_L_BYTES + ((size_t)((t * 4 + grp) * 512 + col) << 4)) = pk.u;
}

// ---------------- fused per-l GEMM body: R4 geometry + counted-vmcnt DMA pipeline -----------
// Block: 512 thr / 8 waves, BZ z-rows x 256 cols (wave = 32 cols). K=512 in 16 tiles of 32.
// Per phase: ENTRY(vmcnt(2)) -> issue dma(t+1) -> issue B(t+1) -> repack(t) (LDS->LDS cvt,
// XOR-swizzled, R7-proven) -> LGKMBAR -> MFMA with B(t) regs. DMA is dest-register-free, so
// the compiler cannot defeat the hand-counted ledger (R10 crash lesson).
template <int D, int BZ, int OFF>
__device__ __forceinline__ void gemm_body(int zc, int j, const float* __restrict__ x1,
                                          const float* __restrict__ x2,
                                          const char* __restrict__ wsl,
                                          float* __restrict__ out,
                                          char* __restrict__ smem) {
  constexpr int BM = BZ * D;                   // output rows (z,i) per block
  constexpr int R = BM / 16;                   // 16-row MFMA tiles
  constexpr int FRAG = BM * 64;                // frag buffer bytes
  constexpr int CPR = BK * D / 4;              // 16B chunks per z-row (mult of 8)
  constexpr int CH = BZ * CPR;                 // real chunks per tile
  constexpr int CHP = ((CH + 511) / 512) * 512;  // padded: uniform KD per wave
  constexpr int KD = CHP / 512;                // DMA instrs per thread (uniform!)
  constexpr int RAWB_P = CHP * 16;             // padded raw buffer bytes
  constexpr int UNITS = BM * (BK / 8);         // frag 16B units per tile (<=512)

  char* rawbuf = smem;
  char* fragbuf = smem + 2 * RAWB_P;

  const int tid = threadIdx.x;
  const int lane = tid & 63, wave = tid >> 6, llo = lane & 15, lhi = lane >> 4;
  const int z0 = zc * BZ, cb = j * 256;
  const float* xbase = x1 + (size_t)z0 * DIM + OFF;

  f32x4 acc[R][2];
#pragma unroll
  for (int rt = 0; rt < R; ++rt)
#pragma unroll
    for (int ct = 0; ct < 2; ++ct) acc[rt][ct] = (f32x4){0.f, 0.f, 0.f, 0.f};

  // ---- DMA: HBM -> raw[t&1]. LDS dest linear (base + lane*16, required); SOURCE pre-
  // swizzled: LDS chunk c holds global chunk c ^ ((c/CPR)&7) (involution within a z-row).
  // Padded slots (c >= CH) clamp the source (duplicate L2-hit load) to keep counts uniform.
  auto dma = [&](int t) {
    char* ldst = rawbuf + (t & 1) * RAWB_P;
    const float* xs = xbase + t * (BK * D);
#pragma unroll
    for (int k = 0; k < KD; ++k) {
      int c = tid + k * 512;
      int cc = (CHP == CH) ? c : ((c < CH) ? c : (CH - 1));
      int g = cc ^ ((cc / CPR) & 7);
      int rowz = g / CPR;
      int off = g - rowz * CPR;
      __builtin_amdgcn_global_load_lds(
          (const __attribute__((address_space(1))) uint32_t*)(xs + (size_t)rowz * DIM + off * 4),
          (__attribute__((address_space(3))) uint32_t*)(ldst + (size_t)c * 16), 16, 0, 0);
    }
  };

  // ---- repack: raw fp32 (stride-D gather, swizzle-matched) -> frag bf16 units ----
  auto repack = [&](int t) {
    const char* rawt = rawbuf + (t & 1) * RAWB_P;
    int u = tid;
    if (u < UNITS) {  // wave-uniform-ish tail; DS-only, outside the vmcnt ledger
      int kg = u / BM;
      int r = u - kg * BM;
      int z = r / D;
      int i = r - z * D;
      bf16x8 v;
#pragma unroll
      for (int jj = 0; jj < 8; ++jj) {
        int fb = (kg * 8 + jj) * D + i;   // float index within z-row
        int b = z * (CPR * 16) + fb * 4;  // unswizzled byte
        int lb = ((((b >> 4) ^ (z & 7)) << 4) | (b & 15));
        v[jj] = (__bf16)(*(const float*)(rawt + lb));
      }
      *(bf16x8*)(fragbuf + (size_t)u * 16) = v;
    }
  };

  // ---- B fragments for tile t from L2-resident ws (2 col-tiles per wave) ----
  auto load_b = [&](bf16x8 (&b)[2], int t) {
    const char* wt = wsl + (size_t)t * 32768;
#pragma unroll
    for (int ct = 0; ct < 2; ++ct)
      b[ct] = *(const bf16x8*)(wt + ((lhi * 512 + cb + wave * 32 + ct * 16 + llo) << 4));
  };

  auto compute = [&](bf16x8 (&b)[2]) {
#pragma unroll
    for (int rt = 0; rt < R; ++rt) {
      bf16x8 af = *(const bf16x8*)(fragbuf + ((lhi * BM + rt * 16 + llo) << 4));
#pragma unroll
      for (int ct = 0; ct < 2; ++ct)
        acc[rt][ct] = MFMA16(af, b[ct], acc[rt][ct], 0, 0, 0);
    }
  };

  // ---- prologue: queue = [dma(0) x KD, b(0) x 2] ----
  bf16x8 bE[2], bO[2];
  dma(0);
  SB();
  load_b(bE, 0);
  SB();

  // ---- main loop (tt=0..6): unconditional issues -> exact static ledger everywhere ----
#pragma unroll 1
  for (int tt = 0; tt < NT / 2 - 1; ++tt) {
    const int t = 2 * tt;
    // E phase: raw[0] holds tile t
    ENTRY();  // dma(t) retired; bE(t) = 2 newest stay in flight
    dma(t + 1);
    SB();
    load_b(bO, t + 1);
    SB();
    repack(t);
    LGKMBAR();
    compute(bE);  // compiler-counted wait for bE: exactly KD+2 newer ops
    // O phase: raw[1] holds tile t+1
    ENTRY();
    dma(t + 2);
    SB();
    load_b(bE, t + 2);
    SB();
    repack(t + 1);
    LGKMBAR();
    compute(bO);
  }
  // ---- peeled tail (t=14,15): no conditional issues inside the steady loop ----
  ENTRY();
  dma(15);
  SB();
  load_b(bO, 15);
  SB();
  repack(14);
  LGKMBAR();
  compute(bE);
  ENTRY();
  repack(15);
  LGKMBAR();
  compute(bO);

  // ---- epilogue: C/D layout col=lane&15, row=(lane>>4)*4+reg; fold x2[z] here ----
  float* obase = out + (size_t)z0 * DIM + OFF;
#pragma unroll
  for (int rt = 0; rt < R; ++rt) {
#pragma unroll
    for (int reg = 0; reg < 4; ++reg) {
      int row = rt * 16 + lhi * 4 + reg;
      int z = row / D;
      int i = row - z * D;
      float s = x2[z0 + z];
#pragma unroll
      for (int ct = 0; ct < 2; ++ct) {
        int col = cb + wave * 32 + ct * 16 + llo;
        obase[(size_t)z * DIM + col * D + i] = acc[rt][ct][reg] * s;
      }
    }
  }
}

// Fused: [0,2048) -> l2, [2048,4096) -> l1, [4096,4608) -> l0 (R4 grid: FETCH/WRITE-clean).
// zc = b>>1, j = b&1: adjacent bids share the x1 z-slab (L2/L3-absorbed re-read).
__global__ __launch_bounds__(512, 4) void gemm_fused(const float* __restrict__ x1,
                                                     const float* __restrict__ x2,
                                                     const char* __restrict__ ws,
                                                     float* __restrict__ out) {
  // LDS: max over l of 2*RAWB_P + FRAG = l2: 2*16384 + 5120 = 37888 -> 2 blocks/CU fits.
  __shared__ __align__(16) char smem[37888];
  int bid = blockIdx.x;
  if (bid < 2048) {
    gemm_body<5, 16, 2048>(bid >> 1, bid & 1, x1, x2, ws + 2 * (size_t)WS_L_BYTES, out, smem);
  } else if (bid < 4096) {
    int b = bid - 2048;
    gemm_body<3, 16, 512>(b >> 1, b & 1, x1, x2, ws + (size_t)WS_L_BYTES, out, smem);
  } else {
    int b = bid - 4096;
    gemm_body<1, 64, 0>(b >> 1, b & 1, x1, x2, ws, out, smem);
  }
}

extern "C" void kernel_launch(void* const* d_in, const int* in_sizes, int n_in,
                              void* d_out, int out_size, void* d_ws, size_t ws_size,
                              hipStream_t stream) {
  const float* x1 = (const float*)d_in[0];
  const float* x2 = (const float*)d_in[1];
  const float* W0 = (const float*)d_in[2];
  const float* W1 = (const float*)d_in[3];
  const float* W2 = (const float*)d_in[4];
  float* out = (float*)d_out;
  char* ws = (char*)d_ws;

  prepack<<<384, 256, 0, stream>>>(W0, W1, W2, ws);
  gemm_fused<<<4608, 512, 0, stream>>>(x1, x2, ws, out);
}